// Round 2
// baseline (927.917 us; speedup 1.0000x reference)
//
#include <hip/hip_runtime.h>

// MHA: B=2, S=2048, HID=1024, H=16, DK=64. SCALE=1/8, NEG=-1e9.
// Pipeline: [wtrans z=4] -> [gemm q,k,v 128x128] -> [flash attn] -> [gemm out].
// bf16 MFMA 16x16x32; layouts: A[m=lane&15][k=quad*8+j], B^T[n=lane&15][k=quad*8+j],
// C/D col=lane&15, row=quad*4+reg.
// GEMM LDS tiles are unpadded 64-u16 rows with XOR group swizzle (g ^= row&7):
// conflict-free frag reads, and global_load_lds-compatible (lane-linear LDS writes,
// swizzle applied on the global gather address).

typedef __bf16 bf16x8 __attribute__((ext_vector_type(8)));
typedef float f32x4 __attribute__((ext_vector_type(4)));
typedef unsigned short u16x8 __attribute__((ext_vector_type(8)));

#define NEGV (-1000000000.0f)

typedef __attribute__((address_space(3))) unsigned int lds_u32;
typedef const __attribute__((address_space(1))) unsigned int glb_u32;

static __device__ __forceinline__ void async16(const void* g, void* l) {
  __builtin_amdgcn_global_load_lds((glb_u32*)g, (lds_u32*)l, 16, 0, 0);
}

static __device__ __forceinline__ unsigned short f2b(float f) {
  unsigned int u = __float_as_uint(f);
  return (unsigned short)((u + 0x7FFFu + ((u >> 16) & 1u)) >> 16);
}

static __device__ __forceinline__ bf16x8 ld8(const unsigned short* p) {
  return __builtin_bit_cast(bf16x8, *(const u16x8*)p);
}

// ---- transpose 1024x1024 fp32 W -> bf16 W^T (N x K), batched over z ----
__global__ __launch_bounds__(256) void k_wtrans(const float* __restrict__ W0, const float* __restrict__ W1,
                                                const float* __restrict__ W2, const float* __restrict__ W3,
                                                unsigned short* __restrict__ T0, unsigned short* __restrict__ T1,
                                                unsigned short* __restrict__ T2, unsigned short* __restrict__ T3) {
  const float* W = (blockIdx.z == 0) ? W0 : (blockIdx.z == 1) ? W1 : (blockIdx.z == 2) ? W2 : W3;
  unsigned short* Wt = (blockIdx.z == 0) ? T0 : (blockIdx.z == 1) ? T1 : (blockIdx.z == 2) ? T2 : T3;
  __shared__ float tile[32][33];
  int k0 = blockIdx.x * 32, n0 = blockIdx.y * 32;
  int tx = threadIdx.x, ty = threadIdx.y;
  #pragma unroll
  for (int i = 0; i < 32; i += 8)
    tile[ty + i][tx] = W[(size_t)(k0 + ty + i) * 1024 + n0 + tx];
  __syncthreads();
  #pragma unroll
  for (int i = 0; i < 32; i += 8)
    Wt[(size_t)(n0 + ty + i) * 1024 + k0 + tx] = f2b(tile[tx][ty + i]);
}

// ---- GEMM: Y(4096x1024) = A(4096x1024) @ Bt^T + bias, 128x128 tile ----
// mode 0: A=q fp32,  out=qh bf16 (B,H,S,DK) scaled 1/8
// mode 1: A=k fp32,  out=kh bf16 (B,H,S,DK)
// mode 2: A=v fp32,  out=vt bf16 (B,H,DK,S)  (transposed epilogue)
// mode 3: A=xb bf16 (global_load_lds), out=fp32 (B,S,1024)
__global__ __launch_bounds__(256) void k_gemm(const float* __restrict__ Af,
                                              const unsigned short* __restrict__ Ab,
                                              const unsigned short* __restrict__ Bt,
                                              const float* __restrict__ bias,
                                              unsigned short* __restrict__ outb,
                                              float* __restrict__ outf, int mode) {
  __shared__ __align__(16) unsigned short smem[128 * 136];  // 34.8 KB (stage + epilogue union)
  unsigned short* As = smem;             // [128][64], swizzled groups
  unsigned short* Bs = smem + 128 * 64;  // [128][64], swizzled groups
  int t = threadIdx.x;
  int wave = t >> 6, lane = t & 63;
  int r16 = lane & 15, quad = lane >> 4, quad8 = quad * 8;
  int wm = (wave >> 1) * 64, wn = (wave & 1) * 64;
  int n0 = blockIdx.x * 128, m0 = blockIdx.y * 128;
  f32x4 acc[4][4] = {};

  for (int k0 = 0; k0 < 1024; k0 += 64) {
    __syncthreads();
    if (mode != 3) {  // fp32 A -> bf16 LDS, coalesced 8-lane rows, swizzled write
      int g = t & 7;
      #pragma unroll
      for (int rr = 0; rr < 4; rr++) {
        int row = (t >> 3) + rr * 32;
        const float* p = Af + (size_t)(m0 + row) * 1024 + k0 + g * 8;
        float4 f0 = *(const float4*)p;
        float4 f1 = *(const float4*)(p + 4);
        u16x8 h;
        h[0] = f2b(f0.x); h[1] = f2b(f0.y); h[2] = f2b(f0.z); h[3] = f2b(f0.w);
        h[4] = f2b(f1.x); h[5] = f2b(f1.y); h[6] = f2b(f1.z); h[7] = f2b(f1.w);
        *(u16x8*)&As[row * 64 + ((g ^ (row & 7))) * 8] = h;
      }
    } else {  // bf16 A via async copy; swizzle via global gather address
      #pragma unroll
      for (int i = 0; i < 4; i++) {
        int row = wave * 32 + i * 8 + (lane >> 3);
        const unsigned short* g = Ab + (size_t)(m0 + row) * 1024 + k0 + (((lane & 7) ^ (row & 7))) * 8;
        async16(g, &As[(wave * 32 + i * 8) * 64]);
      }
    }
    #pragma unroll
    for (int i = 0; i < 4; i++) {  // B via async copy, swizzled gather
      int row = wave * 32 + i * 8 + (lane >> 3);
      const unsigned short* g = Bt + (size_t)(n0 + row) * 1024 + k0 + (((lane & 7) ^ (row & 7))) * 8;
      async16(g, &Bs[(wave * 32 + i * 8) * 64]);
    }
    __syncthreads();
    #pragma unroll
    for (int kk2 = 0; kk2 < 2; kk2++) {
      bf16x8 av[4], bv[4];
      int gq = quad + kk2 * 4;
      #pragma unroll
      for (int mt = 0; mt < 4; mt++) {
        int lm = wm + mt * 16 + r16;
        av[mt] = ld8(&As[lm * 64 + (gq ^ (lm & 7)) * 8]);
      }
      #pragma unroll
      for (int nt = 0; nt < 4; nt++) {
        int ln = wn + nt * 16 + r16;
        bv[nt] = ld8(&Bs[ln * 64 + (gq ^ (ln & 7)) * 8]);
      }
      #pragma unroll
      for (int mt = 0; mt < 4; mt++)
        #pragma unroll
        for (int nt = 0; nt < 4; nt++)
          acc[mt][nt] = __builtin_amdgcn_mfma_f32_16x16x32_bf16(av[mt], bv[nt], acc[mt][nt], 0, 0, 0);
    }
  }

  if (mode == 3) {
    #pragma unroll
    for (int nt = 0; nt < 4; nt++) {
      int gn = n0 + wn + nt * 16 + r16;
      float bv = bias[gn];
      #pragma unroll
      for (int mt = 0; mt < 4; mt++)
        #pragma unroll
        for (int r = 0; r < 4; r++) {
          int gm = m0 + wm + mt * 16 + quad * 4 + r;
          outf[(size_t)gm * 1024 + gn] = acc[mt][nt][r] + bv;
        }
    }
    return;
  }

  __syncthreads();  // staging reads done; smem becomes epilogue buffer [128][136]
  float scale = (mode == 0) ? 0.125f : 1.0f;
  #pragma unroll
  for (int nt = 0; nt < 4; nt++) {
    int ln = wn + nt * 16 + r16;
    float bv = bias[n0 + ln];
    #pragma unroll
    for (int mt = 0; mt < 4; mt++)
      #pragma unroll
      for (int r = 0; r < 4; r++) {
        int lm = wm + mt * 16 + quad * 4 + r;
        unsigned short hv = f2b((acc[mt][nt][r] + bv) * scale);
        if (mode == 2) smem[ln * 136 + lm] = hv;   // transposed: [n][m]
        else           smem[lm * 136 + ln] = hv;   // [m][n]
      }
  }
  __syncthreads();
  int rrow = t >> 1, half = t & 1;
  const unsigned short* src = smem + rrow * 136 + half * 64;  // 136*2=272B rows: 16B-aligned
  if (mode == 2) {
    int b = m0 >> 11, s0 = m0 & 2047;
    int gn = n0 + rrow, h = gn >> 6, d = gn & 63;
    unsigned short* dst = outb + ((size_t)(b * 16 + h) * 64 + d) * 2048 + s0 + half * 64;
    #pragma unroll
    for (int j = 0; j < 8; j++) *(int4*)(dst + j * 8) = *(const int4*)(src + j * 8);
  } else {
    int gm = m0 + rrow, b = gm >> 11, s = gm & 2047;
    int h = (n0 + half * 64) >> 6;
    unsigned short* dst = outb + ((size_t)(b * 16 + h) * 2048 + s) * 64;
    #pragma unroll
    for (int j = 0; j < 8; j++) *(int4*)(dst + j * 8) = *(const int4*)(src + j * 8);
  }
}

// ---- flash attention: per (q-tile 64, b*h) block ----
__global__ __launch_bounds__(256) void k_attn(const unsigned short* __restrict__ qh,
                                              const unsigned short* __restrict__ kh,
                                              const unsigned short* __restrict__ vt,
                                              const float* __restrict__ bias,
                                              const int* __restrict__ mask,
                                              unsigned short* __restrict__ xb) {
  __shared__ __align__(16) unsigned short Ks[64 * 72];
  __shared__ __align__(16) unsigned short Vs[64 * 72];
  __shared__ __align__(16) unsigned short Ps[64 * 72];
  __shared__ float kmb[64];
  int t = threadIdx.x;
  int wave = t >> 6, lane = t & 63;
  int r16 = lane & 15, quad = lane >> 4, quad8 = quad * 8;
  int w16 = wave * 16;
  int q0 = blockIdx.x * 64;
  int bh = blockIdx.y;
  int b = bh >> 4, h = bh & 15;
  const unsigned short* kbase = kh + (size_t)bh * 2048 * 64;
  const unsigned short* vbase = vt + (size_t)bh * 64 * 2048;
  const float* bbase = bias + (size_t)bh * 2048 * 2048 + (size_t)q0 * 2048;

  // Q fragments live in registers for the whole K-loop (A-layout is directly
  // addressable from the (B,H,S,DK) global layout).
  bf16x8 qf[2];
  {
    const unsigned short* qrow = qh + (size_t)bh * 2048 * 64 + (size_t)(q0 + w16 + r16) * 64;
    qf[0] = ld8(qrow + quad8);
    qf[1] = ld8(qrow + 32 + quad8);
  }
  const u16x8 onesu = {0x3F80, 0x3F80, 0x3F80, 0x3F80, 0x3F80, 0x3F80, 0x3F80, 0x3F80};
  const bf16x8 ones = __builtin_bit_cast(bf16x8, onesu);

  f32x4 o[4] = {};
  f32x4 accl = {};  // row-sums l via MFMA against ones (alpha-rescaled like o)
  float mrow[4] = {-1e38f, -1e38f, -1e38f, -1e38f};

  for (int k0 = 0; k0 < 2048; k0 += 64) {
    __syncthreads();  // prev iter LDS reads done
    {                 // stage K (64 keys x 64 d) and V^T (64 d x 64 keys)
      int row = t >> 2, c = (t & 3) * 16;
      *(int4*)&Ks[row * 72 + c]     = *(const int4*)(kbase + (size_t)(k0 + row) * 64 + c);
      *(int4*)&Ks[row * 72 + c + 8] = *(const int4*)(kbase + (size_t)(k0 + row) * 64 + c + 8);
      *(int4*)&Vs[row * 72 + c]     = *(const int4*)(vbase + (size_t)row * 2048 + k0 + c);
      *(int4*)&Vs[row * 72 + c + 8] = *(const int4*)(vbase + (size_t)row * 2048 + k0 + c + 8);
    }
    if (t < 64) kmb[t] = (mask[b * 2048 + k0 + t] == 0) ? 1.0f : 0.0f;
    __syncthreads();

    // S = Q K^T  (Q pre-scaled by 1/8 in projection)
    f32x4 sc[4] = {};
    #pragma unroll
    for (int kk2 = 0; kk2 < 2; kk2++) {
      #pragma unroll
      for (int nt = 0; nt < 4; nt++) {
        bf16x8 bb = ld8(&Ks[(nt * 16 + r16) * 72 + kk2 * 32 + quad8]);
        sc[nt] = __builtin_amdgcn_mfma_f32_16x16x32_bf16(qf[kk2], bb, sc[nt], 0, 0, 0);
      }
    }
    // key-mask -> NEG, then + bias (reference order)
    #pragma unroll
    for (int nt = 0; nt < 4; nt++) {
      float km = kmb[nt * 16 + r16];
      #pragma unroll
      for (int r = 0; r < 4; r++) {
        float bval = bbase[(size_t)(w16 + quad * 4 + r) * 2048 + k0 + nt * 16 + r16];
        sc[nt][r] = ((km > 0.5f) ? NEGV : sc[nt][r]) + bval;
      }
    }
    // online softmax: only the row-max needs shuffles; row-sum comes free via ones-MFMA
    float arow[4];
    #pragma unroll
    for (int r = 0; r < 4; r++) {
      float mx = fmaxf(fmaxf(sc[0][r], sc[1][r]), fmaxf(sc[2][r], sc[3][r]));
      #pragma unroll
      for (int off = 1; off < 16; off <<= 1) mx = fmaxf(mx, __shfl_xor(mx, off));
      float mn = fmaxf(mrow[r], mx);
      arow[r] = __expf(mrow[r] - mn);
      mrow[r] = mn;
      #pragma unroll
      for (int nt = 0; nt < 4; nt++) sc[nt][r] = __expf(sc[nt][r] - mn);
    }
    // P: C-layout -> A-layout via LDS (wave-private rows)
    #pragma unroll
    for (int nt = 0; nt < 4; nt++)
      #pragma unroll
      for (int r = 0; r < 4; r++)
        Ps[(w16 + quad * 4 + r) * 72 + nt * 16 + r16] = f2b(sc[nt][r]);
    #pragma unroll
    for (int r = 0; r < 4; r++) {
      accl[r] *= arow[r];
      #pragma unroll
      for (int nt = 0; nt < 4; nt++) o[nt][r] *= arow[r];
    }
    // O += P V ; l += P @ 1
    #pragma unroll
    for (int kk2 = 0; kk2 < 2; kk2++) {
      bf16x8 a = ld8(&Ps[(w16 + r16) * 72 + kk2 * 32 + quad8]);
      accl = __builtin_amdgcn_mfma_f32_16x16x32_bf16(a, ones, accl, 0, 0, 0);
      #pragma unroll
      for (int nt = 0; nt < 4; nt++) {
        bf16x8 bb = ld8(&Vs[(nt * 16 + r16) * 72 + kk2 * 32 + quad8]);
        o[nt] = __builtin_amdgcn_mfma_f32_16x16x32_bf16(a, bb, o[nt], 0, 0, 0);
      }
    }
  }

  float inv[4];
  #pragma unroll
  for (int r = 0; r < 4; r++) {
    int gq = q0 + w16 + quad * 4 + r;
    float qm = (mask[b * 2048 + gq] != 0) ? 1.0f : 0.0f;
    inv[r] = qm / accl[r];  // l > 0 whenever any key of this batch is unmasked
  }
  #pragma unroll
  for (int nt = 0; nt < 4; nt++)
    #pragma unroll
    for (int r = 0; r < 4; r++) {
      int gq = q0 + w16 + quad * 4 + r;
      xb[(size_t)(b * 2048 + gq) * 1024 + h * 64 + nt * 16 + r16] = f2b(o[nt][r] * inv[r]);
    }
}

extern "C" void kernel_launch(void* const* d_in, const int* in_sizes, int n_in,
                              void* d_out, int out_size, void* d_ws, size_t ws_size,
                              hipStream_t stream) {
  const float* q = (const float*)d_in[0];
  const float* k = (const float*)d_in[1];
  const float* v = (const float*)d_in[2];
  const float* attn_bias = (const float*)d_in[3];
  const int* mask = (const int*)d_in[4];
  const float* Wq = (const float*)d_in[5];
  const float* bq = (const float*)d_in[6];
  const float* Wk = (const float*)d_in[7];
  const float* bk = (const float*)d_in[8];
  const float* Wv = (const float*)d_in[9];
  const float* bv = (const float*)d_in[10];
  const float* Wo = (const float*)d_in[11];
  const float* bo = (const float*)d_in[12];

  char* ws = (char*)d_ws;
  const size_t MB = 1u << 20;
  unsigned short* Wqt = (unsigned short*)(ws + 0 * MB);
  unsigned short* Wkt = (unsigned short*)(ws + 2 * MB);
  unsigned short* Wvt = (unsigned short*)(ws + 4 * MB);
  unsigned short* Wot = (unsigned short*)(ws + 6 * MB);
  unsigned short* qhb = (unsigned short*)(ws + 8 * MB);
  unsigned short* khb = (unsigned short*)(ws + 16 * MB);
  unsigned short* vtb = (unsigned short*)(ws + 24 * MB);
  unsigned short* xbb = (unsigned short*)(ws + 32 * MB);

  k_wtrans<<<dim3(32, 32, 4), dim3(32, 8), 0, stream>>>(Wq, Wk, Wv, Wo, Wqt, Wkt, Wvt, Wot);

  dim3 gg(8, 32), gb(256);
  k_gemm<<<gg, gb, 0, stream>>>(q, nullptr, Wqt, bq, qhb, nullptr, 0);
  k_gemm<<<gg, gb, 0, stream>>>(k, nullptr, Wkt, bk, khb, nullptr, 1);
  k_gemm<<<gg, gb, 0, stream>>>(v, nullptr, Wvt, bv, vtb, nullptr, 2);

  k_attn<<<dim3(32, 32), 256, 0, stream>>>(qhb, khb, vtb, attn_bias, mask, xbb);

  k_gemm<<<gg, gb, 0, stream>>>(nullptr, xbb, Wot, bo, nullptr, (float*)d_out, 3);
}

// Round 3
// 885.413 us; speedup vs baseline: 1.0480x; 1.0480x over previous
//
#include <hip/hip_runtime.h>

// MHA: B=2, S=2048, HID=1024, H=16, DK=64. SCALE=1/8, NEG=-1e9.
// Pipeline: [wtrans z=4] -> [fused qkv gemm z=3, 128x128] -> [flash attn q128]
//           -> [out gemm 64x64].
// bf16 MFMA 16x16x32; layouts: A[m=lane&15][k=quad*8+j], B^T[n=lane&15][k=quad*8+j],
// C/D col=lane&15, row=quad*4+reg.
// LDS tiles: unpadded 64-u16 rows, XOR group swizzle (g ^= row&7) -> conflict-free
// frag reads AND global_load_lds-compatible (lane-linear LDS writes; swizzle applied
// to the global gather address).

typedef __bf16 bf16x8 __attribute__((ext_vector_type(8)));
typedef float f32x4 __attribute__((ext_vector_type(4)));
typedef unsigned short u16x8 __attribute__((ext_vector_type(8)));

#define NEGV (-1000000000.0f)

typedef __attribute__((address_space(3))) unsigned int lds_u32;
typedef const __attribute__((address_space(1))) unsigned int glb_u32;

static __device__ __forceinline__ void async16(const void* g, void* l) {
  __builtin_amdgcn_global_load_lds((glb_u32*)g, (lds_u32*)l, 16, 0, 0);
}

static __device__ __forceinline__ unsigned short f2b(float f) {
  unsigned int u = __float_as_uint(f);
  return (unsigned short)((u + 0x7FFFu + ((u >> 16) & 1u)) >> 16);
}

static __device__ __forceinline__ bf16x8 ld8(const unsigned short* p) {
  return __builtin_bit_cast(bf16x8, *(const u16x8*)p);
}

// ---- transpose 1024x1024 fp32 W -> bf16 W^T (N x K), batched over z ----
__global__ __launch_bounds__(256) void k_wtrans(const float* __restrict__ W0, const float* __restrict__ W1,
                                                const float* __restrict__ W2, const float* __restrict__ W3,
                                                unsigned short* __restrict__ T0, unsigned short* __restrict__ T1,
                                                unsigned short* __restrict__ T2, unsigned short* __restrict__ T3) {
  const float* W = (blockIdx.z == 0) ? W0 : (blockIdx.z == 1) ? W1 : (blockIdx.z == 2) ? W2 : W3;
  unsigned short* Wt = (blockIdx.z == 0) ? T0 : (blockIdx.z == 1) ? T1 : (blockIdx.z == 2) ? T2 : T3;
  __shared__ float tile[32][33];
  int k0 = blockIdx.x * 32, n0 = blockIdx.y * 32;
  int tx = threadIdx.x, ty = threadIdx.y;
  #pragma unroll
  for (int i = 0; i < 32; i += 8)
    tile[ty + i][tx] = W[(size_t)(k0 + ty + i) * 1024 + n0 + tx];
  __syncthreads();
  #pragma unroll
  for (int i = 0; i < 32; i += 8)
    Wt[(size_t)(n0 + ty + i) * 1024 + k0 + tx] = f2b(tile[tx][ty + i]);
}

// ---- fused QKV GEMM: Y(4096x1024) = A @ Wt^T + bias, 128x128 tile, z=mode ----
// mode 0: A=q, out=qh bf16 (B,H,S,DK) scaled 1/8
// mode 1: A=k, out=kh bf16 (B,H,S,DK)
// mode 2: A=v, out=vt bf16 (B,H,DK,S)  (transposed epilogue)
__global__ __launch_bounds__(256) void k_gemm_qkv(
    const float* __restrict__ A0, const float* __restrict__ A1, const float* __restrict__ A2,
    const unsigned short* __restrict__ W0, const unsigned short* __restrict__ W1,
    const unsigned short* __restrict__ W2,
    const float* __restrict__ b0, const float* __restrict__ b1, const float* __restrict__ b2,
    unsigned short* __restrict__ o0, unsigned short* __restrict__ o1, unsigned short* __restrict__ o2) {
  int mode = blockIdx.z;
  const float* Af = (mode == 0) ? A0 : (mode == 1) ? A1 : A2;
  const unsigned short* Bt = (mode == 0) ? W0 : (mode == 1) ? W1 : W2;
  const float* bias = (mode == 0) ? b0 : (mode == 1) ? b1 : b2;
  unsigned short* outb = (mode == 0) ? o0 : (mode == 1) ? o1 : o2;

  __shared__ __align__(16) unsigned short smem[128 * 136];  // stage + epilogue union
  unsigned short* As = smem;             // [128][64], swizzled groups
  unsigned short* Bs = smem + 128 * 64;  // [128][64], swizzled groups
  int t = threadIdx.x;
  int wave = t >> 6, lane = t & 63;
  int r16 = lane & 15, quad = lane >> 4;
  int wm = (wave >> 1) * 64, wn = (wave & 1) * 64;
  int n0 = blockIdx.x * 128, m0 = blockIdx.y * 128;
  f32x4 acc[4][4] = {};

  for (int k0 = 0; k0 < 1024; k0 += 64) {
    __syncthreads();
    {  // fp32 A -> bf16 LDS, coalesced 8-lane rows, swizzled write
      int g = t & 7;
      #pragma unroll
      for (int rr = 0; rr < 4; rr++) {
        int row = (t >> 3) + rr * 32;
        const float* p = Af + (size_t)(m0 + row) * 1024 + k0 + g * 8;
        float4 f0 = *(const float4*)p;
        float4 f1 = *(const float4*)(p + 4);
        u16x8 h;
        h[0] = f2b(f0.x); h[1] = f2b(f0.y); h[2] = f2b(f0.z); h[3] = f2b(f0.w);
        h[4] = f2b(f1.x); h[5] = f2b(f1.y); h[6] = f2b(f1.z); h[7] = f2b(f1.w);
        *(u16x8*)&As[row * 64 + ((g ^ (row & 7))) * 8] = h;
      }
    }
    #pragma unroll
    for (int i = 0; i < 4; i++) {  // W^T via async copy, swizzled gather
      int row = wave * 32 + i * 8 + (lane >> 3);
      const unsigned short* g = Bt + (size_t)(n0 + row) * 1024 + k0 + (((lane & 7) ^ (row & 7))) * 8;
      async16(g, &Bs[(wave * 32 + i * 8) * 64]);
    }
    __syncthreads();
    #pragma unroll
    for (int kk2 = 0; kk2 < 2; kk2++) {
      bf16x8 av[4], bv[4];
      int gq = quad + kk2 * 4;
      #pragma unroll
      for (int mt = 0; mt < 4; mt++) {
        int lm = wm + mt * 16 + r16;
        av[mt] = ld8(&As[lm * 64 + (gq ^ (lm & 7)) * 8]);
      }
      #pragma unroll
      for (int nt = 0; nt < 4; nt++) {
        int ln = wn + nt * 16 + r16;
        bv[nt] = ld8(&Bs[ln * 64 + (gq ^ (ln & 7)) * 8]);
      }
      #pragma unroll
      for (int mt = 0; mt < 4; mt++)
        #pragma unroll
        for (int nt = 0; nt < 4; nt++)
          acc[mt][nt] = __builtin_amdgcn_mfma_f32_16x16x32_bf16(av[mt], bv[nt], acc[mt][nt], 0, 0, 0);
    }
  }

  __syncthreads();  // staging reads done; smem becomes epilogue buffer [128][136]
  float scale = (mode == 0) ? 0.125f : 1.0f;
  #pragma unroll
  for (int nt = 0; nt < 4; nt++) {
    int ln = wn + nt * 16 + r16;
    float bv = bias[n0 + ln];
    #pragma unroll
    for (int mt = 0; mt < 4; mt++)
      #pragma unroll
      for (int r = 0; r < 4; r++) {
        int lm = wm + mt * 16 + quad * 4 + r;
        unsigned short hv = f2b((acc[mt][nt][r] + bv) * scale);
        if (mode == 2) smem[ln * 136 + lm] = hv;   // transposed: [n][m]
        else           smem[lm * 136 + ln] = hv;   // [m][n]
      }
  }
  __syncthreads();
  int rrow = t >> 1, half = t & 1;
  const unsigned short* src = smem + rrow * 136 + half * 64;
  if (mode == 2) {
    int b = m0 >> 11, s0 = m0 & 2047;
    int gn = n0 + rrow, h = gn >> 6, d = gn & 63;
    unsigned short* dst = outb + ((size_t)(b * 16 + h) * 64 + d) * 2048 + s0 + half * 64;
    #pragma unroll
    for (int j = 0; j < 8; j++) *(int4*)(dst + j * 8) = *(const int4*)(src + j * 8);
  } else {
    int gm = m0 + rrow, b = gm >> 11, s = gm & 2047;
    int h = (n0 + half * 64) >> 6;
    unsigned short* dst = outb + ((size_t)(b * 16 + h) * 2048 + s) * 64;
    #pragma unroll
    for (int j = 0; j < 8; j++) *(int4*)(dst + j * 8) = *(const int4*)(src + j * 8);
  }
}

// ---- out projection: Y(4096x1024) fp32 = xb(bf16) @ Wot^T + bo, 64x64 tile ----
__global__ __launch_bounds__(256) void k_gemm_o(const unsigned short* __restrict__ Ab,
                                                const unsigned short* __restrict__ Bt,
                                                const float* __restrict__ bias,
                                                float* __restrict__ outf) {
  __shared__ __align__(16) unsigned short As[64 * 64];
  __shared__ __align__(16) unsigned short Bs[64 * 64];
  int t = threadIdx.x;
  int wave = t >> 6, lane = t & 63;
  int r16 = lane & 15, quad = lane >> 4;
  int w16 = wave * 16;
  int n0 = blockIdx.x * 64, m0 = blockIdx.y * 64;
  f32x4 acc[4] = {};

  for (int k0 = 0; k0 < 1024; k0 += 64) {
    __syncthreads();
    #pragma unroll
    for (int i = 0; i < 2; i++) {
      int row = wave * 16 + i * 8 + (lane >> 3);
      const unsigned short* ga = Ab + (size_t)(m0 + row) * 1024 + k0 + (((lane & 7) ^ (row & 7))) * 8;
      async16(ga, &As[(wave * 16 + i * 8) * 64]);
      const unsigned short* gb = Bt + (size_t)(n0 + row) * 1024 + k0 + (((lane & 7) ^ (row & 7))) * 8;
      async16(gb, &Bs[(wave * 16 + i * 8) * 64]);
    }
    __syncthreads();
    #pragma unroll
    for (int kk2 = 0; kk2 < 2; kk2++) {
      int gq = quad + kk2 * 4;
      int lm = w16 + r16;
      bf16x8 a = ld8(&As[lm * 64 + (gq ^ (lm & 7)) * 8]);
      #pragma unroll
      for (int nt = 0; nt < 4; nt++) {
        int ln = nt * 16 + r16;
        bf16x8 bb = ld8(&Bs[ln * 64 + (gq ^ (ln & 7)) * 8]);
        acc[nt] = __builtin_amdgcn_mfma_f32_16x16x32_bf16(a, bb, acc[nt], 0, 0, 0);
      }
    }
  }
  #pragma unroll
  for (int nt = 0; nt < 4; nt++) {
    int gn = n0 + nt * 16 + r16;
    float bv = bias[gn];
    #pragma unroll
    for (int r = 0; r < 4; r++) {
      int gm = m0 + w16 + quad * 4 + r;
      outf[(size_t)gm * 1024 + gn] = acc[nt][r] + bv;
    }
  }
}

// ---- flash attention: q-tile 128, k-tile 64, per (q-tile, b*h) block ----
__global__ __launch_bounds__(256) void k_attn(const unsigned short* __restrict__ qh,
                                              const unsigned short* __restrict__ kh,
                                              const unsigned short* __restrict__ vt,
                                              const float* __restrict__ bias,
                                              const int* __restrict__ mask,
                                              unsigned short* __restrict__ xb) {
  __shared__ __align__(16) unsigned short Ks[64 * 64];   // swizzled [key][d]
  __shared__ __align__(16) unsigned short Vs[64 * 64];   // swizzled [d][key]
  __shared__ __align__(16) unsigned short Ps[128 * 72];  // padded   [q][key]
  __shared__ float kmb[64];
  int t = threadIdx.x;
  int wave = t >> 6, lane = t & 63;
  int r16 = lane & 15, quad = lane >> 4, quad8 = quad * 8;
  int w32 = wave * 32;
  int q0 = blockIdx.x * 128;
  int bh = blockIdx.y;
  int b = bh >> 4, h = bh & 15;
  const unsigned short* kbase = kh + (size_t)bh * 2048 * 64;
  const unsigned short* vbase = vt + (size_t)bh * 64 * 2048;
  const float* bbase = bias + (size_t)bh * 2048 * 2048 + (size_t)q0 * 2048;

  // Q fragments in registers for the whole K-loop (2 m-frags x 2 k-halves)
  bf16x8 qf[2][2];
  #pragma unroll
  for (int mt = 0; mt < 2; mt++) {
    const unsigned short* qrow = qh + (size_t)bh * 2048 * 64 + (size_t)(q0 + w32 + mt * 16 + r16) * 64;
    qf[mt][0] = ld8(qrow + quad8);
    qf[mt][1] = ld8(qrow + 32 + quad8);
  }
  const u16x8 onesu = {0x3F80, 0x3F80, 0x3F80, 0x3F80, 0x3F80, 0x3F80, 0x3F80, 0x3F80};
  const bf16x8 ones = __builtin_bit_cast(bf16x8, onesu);

  f32x4 o[2][4] = {};
  f32x4 accl[2] = {};  // row-sums l via MFMA vs ones, alpha-rescaled like o
  float mrow[2][4] = {{-1e38f, -1e38f, -1e38f, -1e38f}, {-1e38f, -1e38f, -1e38f, -1e38f}};

  for (int k0 = 0; k0 < 2048; k0 += 64) {
    __syncthreads();  // prev iter frag reads done
    #pragma unroll
    for (int j = 0; j < 2; j++) {  // stage K and V^T via async, swizzled gather
      int row = wave * 16 + j * 8 + (lane >> 3);
      int sw = (((lane & 7) ^ (row & 7))) * 8;
      async16(kbase + (size_t)(k0 + row) * 64 + sw, &Ks[(wave * 16 + j * 8) * 64]);
      async16(vbase + (size_t)row * 2048 + k0 + sw, &Vs[(wave * 16 + j * 8) * 64]);
    }
    if (t < 64) kmb[t] = (mask[b * 2048 + k0 + t] == 0) ? 1.0f : 0.0f;
    __syncthreads();

    // S = Q K^T  (Q pre-scaled by 1/8 in projection)
    f32x4 sc[2][4] = {};
    #pragma unroll
    for (int kk2 = 0; kk2 < 2; kk2++) {
      bf16x8 kf[4];
      int gq = quad + kk2 * 4;
      #pragma unroll
      for (int nt = 0; nt < 4; nt++) {
        int ln = nt * 16 + r16;
        kf[nt] = ld8(&Ks[ln * 64 + (gq ^ (ln & 7)) * 8]);
      }
      #pragma unroll
      for (int mt = 0; mt < 2; mt++)
        #pragma unroll
        for (int nt = 0; nt < 4; nt++)
          sc[mt][nt] = __builtin_amdgcn_mfma_f32_16x16x32_bf16(qf[mt][kk2], kf[nt], sc[mt][nt], 0, 0, 0);
    }
    // key-mask -> NEG, then + bias (reference order)
    #pragma unroll
    for (int mt = 0; mt < 2; mt++)
      #pragma unroll
      for (int nt = 0; nt < 4; nt++) {
        float km = kmb[nt * 16 + r16];
        #pragma unroll
        for (int r = 0; r < 4; r++) {
          float bval = bbase[(size_t)(w32 + mt * 16 + quad * 4 + r) * 2048 + k0 + nt * 16 + r16];
          sc[mt][nt][r] = ((km > 0.5f) ? NEGV : sc[mt][nt][r]) + bval;
        }
      }
    // online softmax: row-max via shuffles; row-sum free via ones-MFMA
    float arow[2][4];
    #pragma unroll
    for (int mt = 0; mt < 2; mt++)
      #pragma unroll
      for (int r = 0; r < 4; r++) {
        float mx = fmaxf(fmaxf(sc[mt][0][r], sc[mt][1][r]), fmaxf(sc[mt][2][r], sc[mt][3][r]));
        #pragma unroll
        for (int off = 1; off < 16; off <<= 1) mx = fmaxf(mx, __shfl_xor(mx, off));
        float mn = fmaxf(mrow[mt][r], mx);
        arow[mt][r] = __expf(mrow[mt][r] - mn);
        mrow[mt][r] = mn;
        #pragma unroll
        for (int nt = 0; nt < 4; nt++) sc[mt][nt][r] = __expf(sc[mt][nt][r] - mn);
      }
    // P: C-layout -> A-layout via LDS (wave-private rows, no barrier needed)
    #pragma unroll
    for (int mt = 0; mt < 2; mt++)
      #pragma unroll
      for (int nt = 0; nt < 4; nt++)
        #pragma unroll
        for (int r = 0; r < 4; r++)
          Ps[(w32 + mt * 16 + quad * 4 + r) * 72 + nt * 16 + r16] = f2b(sc[mt][nt][r]);
    #pragma unroll
    for (int mt = 0; mt < 2; mt++)
      #pragma unroll
      for (int r = 0; r < 4; r++) {
        accl[mt][r] *= arow[mt][r];
        #pragma unroll
        for (int nt = 0; nt < 4; nt++) o[mt][nt][r] *= arow[mt][r];
      }
    // O += P V ; l += P @ 1
    #pragma unroll
    for (int kk2 = 0; kk2 < 2; kk2++) {
      bf16x8 vf[4];
      int gq = quad + kk2 * 4;
      #pragma unroll
      for (int nt = 0; nt < 4; nt++) {
        int ln = nt * 16 + r16;
        vf[nt] = ld8(&Vs[ln * 64 + (gq ^ (ln & 7)) * 8]);
      }
      #pragma unroll
      for (int mt = 0; mt < 2; mt++) {
        bf16x8 a = ld8(&Ps[(w32 + mt * 16 + r16) * 72 + kk2 * 32 + quad8]);
        accl[mt] = __builtin_amdgcn_mfma_f32_16x16x32_bf16(a, ones, accl[mt], 0, 0, 0);
        #pragma unroll
        for (int nt = 0; nt < 4; nt++)
          o[mt][nt] = __builtin_amdgcn_mfma_f32_16x16x32_bf16(a, vf[nt], o[mt][nt], 0, 0, 0);
      }
    }
  }

  #pragma unroll
  for (int mt = 0; mt < 2; mt++) {
    float inv[4];
    #pragma unroll
    for (int r = 0; r < 4; r++) {
      int gq = q0 + w32 + mt * 16 + quad * 4 + r;
      float qm = (mask[b * 2048 + gq] != 0) ? 1.0f : 0.0f;
      inv[r] = qm / accl[mt][r];
    }
    #pragma unroll
    for (int nt = 0; nt < 4; nt++)
      #pragma unroll
      for (int r = 0; r < 4; r++) {
        int gq = q0 + w32 + mt * 16 + quad * 4 + r;
        xb[(size_t)(b * 2048 + gq) * 1024 + h * 64 + nt * 16 + r16] = f2b(o[mt][nt][r] * inv[r]);
      }
  }
}

extern "C" void kernel_launch(void* const* d_in, const int* in_sizes, int n_in,
                              void* d_out, int out_size, void* d_ws, size_t ws_size,
                              hipStream_t stream) {
  const float* q = (const float*)d_in[0];
  const float* k = (const float*)d_in[1];
  const float* v = (const float*)d_in[2];
  const float* attn_bias = (const float*)d_in[3];
  const int* mask = (const int*)d_in[4];
  const float* Wq = (const float*)d_in[5];
  const float* bq = (const float*)d_in[6];
  const float* Wk = (const float*)d_in[7];
  const float* bk = (const float*)d_in[8];
  const float* Wv = (const float*)d_in[9];
  const float* bv = (const float*)d_in[10];
  const float* Wo = (const float*)d_in[11];
  const float* bo = (const float*)d_in[12];

  char* ws = (char*)d_ws;
  const size_t MB = 1u << 20;
  unsigned short* Wqt = (unsigned short*)(ws + 0 * MB);
  unsigned short* Wkt = (unsigned short*)(ws + 2 * MB);
  unsigned short* Wvt = (unsigned short*)(ws + 4 * MB);
  unsigned short* Wot = (unsigned short*)(ws + 6 * MB);
  unsigned short* qhb = (unsigned short*)(ws + 8 * MB);
  unsigned short* khb = (unsigned short*)(ws + 16 * MB);
  unsigned short* vtb = (unsigned short*)(ws + 24 * MB);
  unsigned short* xbb = (unsigned short*)(ws + 32 * MB);

  k_wtrans<<<dim3(32, 32, 4), dim3(32, 8), 0, stream>>>(Wq, Wk, Wv, Wo, Wqt, Wkt, Wvt, Wot);

  k_gemm_qkv<<<dim3(8, 32, 3), 256, 0, stream>>>(q, k, v, Wqt, Wkt, Wvt, bq, bk, bv,
                                                 qhb, khb, vtb);

  k_attn<<<dim3(16, 32), 256, 0, stream>>>(qhb, khb, vtb, attn_bias, mask, xbb);

  k_gemm_o<<<dim3(16, 64), 256, 0, stream>>>(xbb, Wot, bo, (float*)d_out);
}